// Round 16
// baseline (171.585 us; speedup 1.0000x reference)
//
#include <hip/hip_runtime.h>
#include <hip/hip_bf16.h>
#include <stdint.h>

typedef __bf16 bf16_t;
typedef __bf16 bf16x4 __attribute__((ext_vector_type(4)));
typedef __bf16 bf16x8 __attribute__((ext_vector_type(8)));
typedef float  f32x4  __attribute__((ext_vector_type(4)));

#define B_    4
#define T_    2048
#define C_    1024
#define NH    16
#define HD    64
#define M_TOT (B_ * T_)   // 8192

// async global -> LDS, 16B per lane (dest must be wave-uniform base + lane*16)
__device__ __forceinline__ void gload16(const void* g, void* l) {
    __builtin_amdgcn_global_load_lds(
        (const __attribute__((address_space(1))) uint32_t*)g,
        (__attribute__((address_space(3))) uint32_t*)l, 16, 0, 0);
}

// ---------------- convert x (fp32) -> bf16, flat ----------------
__global__ void conv_x_kernel(const float* __restrict__ x, bf16_t* __restrict__ xb, int n4) {
    int i = blockIdx.x * blockDim.x + threadIdx.x;
    int stride = gridDim.x * blockDim.x;
    for (; i < n4; i += stride) {
        float4 v = reinterpret_cast<const float4*>(x)[i];
        union { bf16_t h[4]; uint2 u; } p;
        p.h[0] = (bf16_t)v.x; p.h[1] = (bf16_t)v.y;
        p.h[2] = (bf16_t)v.z; p.h[3] = (bf16_t)v.w;
        reinterpret_cast<uint2*>(xb)[i] = p.u;
    }
}

// ---------------- transpose + convert: w[K][N] fp32 -> wt[N][K] bf16 ----------------
__global__ void transpose_w_kernel(const float* __restrict__ w, bf16_t* __restrict__ wt,
                                   int K, int N) {
    __shared__ float tile[32][33];
    int n0 = blockIdx.x * 32, k0 = blockIdx.y * 32;
    int tx = threadIdx.x, ty = threadIdx.y;
    #pragma unroll
    for (int i = 0; i < 32; i += 8)
        tile[ty + i][tx] = w[(size_t)(k0 + ty + i) * N + n0 + tx];
    __syncthreads();
    #pragma unroll
    for (int i = 0; i < 32; i += 8)
        wt[(size_t)(n0 + ty + i) * K + k0 + tx] = (bf16_t)tile[tx][ty + i];
}

#define QSCALE 0.18033688011112042f   // (1/8) * log2(e)

// ---------------- 128x128 4-phase GEMM (unchanged, known-good) ----------------
#define LA0 0
#define LA1 16384
#define LB0 32768
#define LB1 49152

#define GST(ptr, rbase, base, kt) do { int k0_ = ((kt) << 6) & (K - 1);           \
    _Pragma("unroll") for (int c_ = 0; c_ < 4; ++c_) {                            \
        int li_ = tid + c_ * 256; int row_ = li_ >> 3;                            \
        int sw_ = (li_ & 7) ^ (row_ & 7);                                         \
        gload16(ptr + (size_t)((rbase) + row_) * K + k0_ + sw_ * 8,               \
                lds + (base) + li_ * 16); } } while (0)

#define GREAD(abase, bbase) do {                                                  \
    _Pragma("unroll") for (int mi_ = 0; mi_ < 4; ++mi_)                           \
        _Pragma("unroll") for (int kk_ = 0; kk_ < 2; ++kk_) {                     \
            int row_  = wm * 64 + mi_ * 16 + q16;                                 \
            int byte_ = (row_ * 128 + kk_ * 64 + g * 16) ^ ((row_ & 7) << 4);     \
            af[mi_ * 2 + kk_] = *reinterpret_cast<const bf16x8*>(lds + (abase) + byte_); } \
    _Pragma("unroll") for (int n_ = 0; n_ < 4; ++n_)                              \
        _Pragma("unroll") for (int kk_ = 0; kk_ < 2; ++kk_) {                     \
            int row_  = wn * 64 + n_ * 16 + q16;                                  \
            int byte_ = (row_ * 128 + kk_ * 64 + g * 16) ^ ((row_ & 7) << 4);     \
            bfr[n_ * 2 + kk_] = *reinterpret_cast<const bf16x8*>(lds + (bbase) + byte_); } } while (0)

#define GMFMA(milo) do { __builtin_amdgcn_s_setprio(1);                           \
    _Pragma("unroll") for (int mi_ = 0; mi_ < 2; ++mi_)                           \
        _Pragma("unroll") for (int kk_ = 0; kk_ < 2; ++kk_)                       \
            _Pragma("unroll") for (int n_ = 0; n_ < 4; ++n_)                      \
                acc[(milo) + mi_][n_] = __builtin_amdgcn_mfma_f32_16x16x32_bf16(  \
                    af[((milo) + mi_) * 2 + kk_], bfr[n_ * 2 + kk_],              \
                    acc[(milo) + mi_][n_], 0, 0, 0);                              \
    __builtin_amdgcn_s_setprio(0); } while (0)

template<int MODE>
__global__ __launch_bounds__(256, 2) void gemm_kernel(
    const bf16_t* __restrict__ A, const bf16_t* __restrict__ Bt,
    float* __restrict__ Cout,
    bf16_t* __restrict__ Qo, bf16_t* __restrict__ Ko, bf16_t* __restrict__ Vt,
    int M, int N, int K)
{
    __shared__ __align__(16) char lds[65536];
    const int tid  = threadIdx.x;
    const int lane = tid & 63;
    const int wid  = tid >> 6;
    const int wm   = wid >> 1, wn = wid & 1;
    const int q16  = lane & 15, g = lane >> 4;
    const int xcd = blockIdx.x & 7;
    const int i0  = blockIdx.x >> 3;
    const int mbase = (xcd * 8 + (i0 & 7)) * 128;
    const int nbase = (i0 >> 3) * 128;
    const int NITER = K >> 7;

    f32x4  acc[4][4] = {};
    bf16x8 af[8], bfr[8];

    GST(A, mbase, LA0, 0); GST(Bt, nbase, LB0, 0);
    GST(A, mbase, LA1, 1); GST(Bt, nbase, LB1, 1);
    asm volatile("s_waitcnt vmcnt(8)" ::: "memory");
    __builtin_amdgcn_s_barrier();
    __builtin_amdgcn_sched_barrier(0);

    #pragma unroll 1
    for (int i = 0; i < NITER; ++i) {
        GREAD(LA0, LB0);
        __builtin_amdgcn_s_barrier();
        asm volatile("s_waitcnt lgkmcnt(0)" ::: "memory");
        __builtin_amdgcn_sched_barrier(0);
        GMFMA(0);
        __builtin_amdgcn_s_barrier();
        GST(A, mbase, LA0, 2 * i + 2); GST(Bt, nbase, LB0, 2 * i + 2);
        __builtin_amdgcn_sched_barrier(0);
        GMFMA(2);
        asm volatile("s_waitcnt vmcnt(8)" ::: "memory");
        __builtin_amdgcn_s_barrier();
        GREAD(LA1, LB1);
        __builtin_amdgcn_s_barrier();
        asm volatile("s_waitcnt lgkmcnt(0)" ::: "memory");
        __builtin_amdgcn_sched_barrier(0);
        GMFMA(0);
        __builtin_amdgcn_s_barrier();
        GST(A, mbase, LA1, 2 * i + 3); GST(Bt, nbase, LB1, 2 * i + 3);
        __builtin_amdgcn_sched_barrier(0);
        GMFMA(2);
        asm volatile("s_waitcnt vmcnt(8)" ::: "memory");
        __builtin_amdgcn_s_barrier();
    }
    asm volatile("s_waitcnt vmcnt(0)" ::: "memory");

    #pragma unroll
    for (int mi = 0; mi < 4; ++mi) {
        #pragma unroll
        for (int n = 0; n < 4; ++n) {
            const int row0 = mbase + wm * 64 + mi * 16 + g * 4;
            const int col0 = nbase + wn * 64 + n * 16;
            if (MODE == 0) {
                #pragma unroll
                for (int r = 0; r < 4; ++r)
                    Cout[(size_t)(row0 + r) * N + col0 + q16] = acc[mi][n][r];
            } else {
                const int b = row0 >> 11, t0 = row0 & 2047;
                if (col0 < 1024) {
                    int h = col0 >> 6, d = (col0 & 63) + q16;
                    #pragma unroll
                    for (int r = 0; r < 4; ++r)
                        Qo[((size_t)(b * NH + h) * T_ + t0 + r) * HD + d] =
                            (bf16_t)(acc[mi][n][r] * QSCALE);
                } else if (col0 < 2048) {
                    int h = (col0 - 1024) >> 6, d = (col0 & 63) + q16;
                    #pragma unroll
                    for (int r = 0; r < 4; ++r)
                        Ko[((size_t)(b * NH + h) * T_ + t0 + r) * HD + d] =
                            (bf16_t)acc[mi][n][r];
                } else {
                    int h = (col0 - 2048) >> 6, d = (col0 & 63) + q16;
                    bf16x4 vv = { (bf16_t)acc[mi][n][0], (bf16_t)acc[mi][n][1],
                                  (bf16_t)acc[mi][n][2], (bf16_t)acc[mi][n][3] };
                    *reinterpret_cast<bf16x4*>(
                        Vt + ((size_t)(b * NH + h) * HD + d) * T_ + t0) = vv;
                }
            }
        }
    }
}

// ---------------- flash attention, kv-split load balance ----------------
// Fixed-base softmax => partial (sum p*v, sum p) over disjoint kv ranges sum
// EXACTLY. Long q-tiles (qt>=8) split into 2 kv-chunks (even tile counts);
// each chunk block stores raw bf16 acc + f32 row-sums to scratch; a combine
// kernel computes (a0+a1)/(l0+l1). All blocks now nt<=16 -> backfill smooths
// the tail that pinned occupancy at 26%.
// 24 job classes/head (1536 blocks); class groups assigned so each CU's six
// jobs sum to 66-70 KV-iters. bid&7 == bh&7 keeps head K/V XCD-pinned.
// Partial scratch lives in the xb/wqkvT region (dead after QKV GEMM).
#define PSLOT 16896   // 128x64 bf16 acc (16384) + 128 f32 l (512)

__constant__ int8_t QT_TAB[24] = {15,15,7,6, 14,14,12,12, 13,13,11,5,
                                  11,10,10,9, 8,3,9,4, 0,1,2,8};
__constant__ int8_t MD_TAB[24] = {2,1,0,0, 2,1,2,1, 2,1,1,0,
                                  2,2,1,1, 2,0,2,0, 0,0,0,1};  // 0=solo,1=chunk0,2=chunk1

__global__ __launch_bounds__(256, 3) void attn_kernel(
    const bf16_t* __restrict__ Q, const bf16_t* __restrict__ K,
    const bf16_t* __restrict__ Vt, bf16_t* __restrict__ out,
    char* __restrict__ pbuf)
{
    __shared__ __align__(16) char kvbuf[2][16384];   // [buf][ K 8KB | V^T 8KB ]
    __shared__ __align__(16) char plds[4][2048];     // per-wave shared P^T patch
    const int tid  = threadIdx.x;
    const int lane = tid & 63;
    const int wid  = tid >> 6;
    const int g    = lane >> 4;
    const int q16  = lane & 15;

    const int bid = blockIdx.x;          // 0..1535
    const int cls = bid >> 6;            // 0..23
    const int bh  = bid & 63;
    const int b   = bh >> 4, h = bh & 15;
    const int qt   = QT_TAB[cls];
    const int mode = MD_TAB[cls];
    const int ntot = 2 * qt + 2;                       // total KV-64 tiles of qt
    const int nt0  = (qt & 1) ? (qt + 1) : (qt + 2);   // even chunk0 size
    const int lo   = (mode == 2) ? nt0 : 0;            // first tile index
    const int nt   = (mode == 0) ? ntot : (mode == 1 ? nt0 : ntot - nt0); // even

    const bf16_t* Qh = Q  + (size_t)bh * T_ * HD;
    const bf16_t* Kh = K  + (size_t)bh * T_ * HD;
    const bf16_t* Vh = Vt + (size_t)bh * HD * T_;
    char* myp = plds[wid];
    const int pswz = (q16 & 7) << 4;

    const int qbase = qt * 128 + wid * 32;
    const int qg0   = qbase + q16;
    const int qg1   = qbase + 16 + q16;

    // ---- loop-invariant LDS byte offsets ----
    int koff[4][2], pwoff[4], proff[2];
    #pragma unroll
    for (int t = 0; t < 4; ++t) {
        #pragma unroll
        for (int kk = 0; kk < 2; ++kk)
            koff[t][kk] = ((t * 16 + q16) * 128 + kk * 64 + g * 16) ^ pswz;
        pwoff[t] = (q16 * 128 + t * 32 + g * 8) ^ pswz;
    }
    proff[0] = (q16 * 128 + g * 16) ^ pswz;
    proff[1] = (q16 * 128 + 64 + g * 16) ^ pswz;

    // ---- moving per-lane staging pointers, starting at tile `lo` ----
    const int li0 = tid,        row0 = li0 >> 3, sw0 = (li0 & 7) ^ (row0 & 7);
    const int li1 = tid + 256,  row1 = li1 >> 3, sw1 = (li1 & 7) ^ (row1 & 7);
    const int kvlo = lo << 6;
    const bf16_t* kS0 = Kh + (size_t)(kvlo + row0) * HD + sw0 * 8;
    const bf16_t* kS1 = Kh + (size_t)(kvlo + row1) * HD + sw1 * 8;
    const bf16_t* vS0 = Vh + (size_t)row0 * T_ + kvlo + sw0 * 8;
    const bf16_t* vS1 = Vh + (size_t)row1 * T_ + kvlo + sw1 * 8;

#define STAGE2(buf) do {                                                          \
        gload16(kS0, (char*)(buf) + tid * 16);                                    \
        gload16(kS1, (char*)(buf) + 4096 + tid * 16);                             \
        gload16(vS0, (char*)(buf) + 8192 + tid * 16);                             \
        gload16(vS1, (char*)(buf) + 12288 + tid * 16);                            \
        kS0 += 4096; kS1 += 4096; vS0 += 64; vS1 += 64; } while (0)

    bf16x8 qf0[2], qf1[2];
    #pragma unroll
    for (int kk = 0; kk < 2; ++kk) {
        qf0[kk] = *reinterpret_cast<const bf16x8*>(Qh + (size_t)qg0 * HD + kk * 32 + g * 8);
        qf1[kk] = *reinterpret_cast<const bf16x8*>(Qh + (size_t)qg1 * HD + kk * 32 + g * 8);
    }

    f32x4 acc0[4] = {}, acc1[4] = {};
    float l0 = 0.f, l1 = 0.f;

#define ABODY(LIT, CURB, NXTB) do {                                               \
    const int kv0 = (lo + (LIT)) << 6;                                            \
    if ((LIT) + 1 < nt) {                                                         \
        STAGE2(NXTB);                                                             \
        asm volatile("s_waitcnt vmcnt(4)" ::: "memory");                          \
    } else {                                                                      \
        asm volatile("s_waitcnt vmcnt(0)" ::: "memory");                          \
    }                                                                             \
    __builtin_amdgcn_s_barrier();                                                 \
    __builtin_amdgcn_sched_barrier(0);                                            \
    const char* Kl = (const char*)(CURB);                                         \
    const char* Vl = (const char*)(CURB) + 8192;                                  \
    f32x4 s0[4] = {}, s1[4] = {};                                                 \
    __builtin_amdgcn_s_setprio(1);                                                \
    _Pragma("unroll") for (int t = 0; t < 4; ++t)                                 \
        _Pragma("unroll") for (int kk = 0; kk < 2; ++kk) {                        \
            bf16x8 kf = *reinterpret_cast<const bf16x8*>(Kl + koff[t][kk]);       \
            s0[t] = __builtin_amdgcn_mfma_f32_16x16x32_bf16(kf, qf0[kk], s0[t], 0, 0, 0); \
            s1[t] = __builtin_amdgcn_mfma_f32_16x16x32_bf16(kf, qf1[kk], s1[t], 0, 0, 0); } \
    __builtin_amdgcn_s_setprio(0);                                                \
    if (kv0 + 63 > qbase) {                                                       \
        _Pragma("unroll") for (int t = 0; t < 4; ++t)                             \
            _Pragma("unroll") for (int r = 0; r < 4; ++r) {                       \
                int kv = kv0 + t * 16 + g * 4 + r;                                \
                if (kv > qg0) s0[t][r] = -1e30f;                                  \
                if (kv > qg1) s1[t][r] = -1e30f; } }                              \
    /* qset0: exp -> shared patch -> PV */                                        \
    _Pragma("unroll") for (int t = 0; t < 4; ++t) {                               \
        float p00 = exp2f(s0[t][0]), p01 = exp2f(s0[t][1]);                       \
        float p02 = exp2f(s0[t][2]), p03 = exp2f(s0[t][3]);                       \
        l0 += (p00 + p01) + (p02 + p03);                                          \
        bf16x4 pw0 = { (bf16_t)p00, (bf16_t)p01, (bf16_t)p02, (bf16_t)p03 };      \
        *reinterpret_cast<bf16x4*>(myp + pwoff[t]) = pw0; }                       \
    asm volatile("s_waitcnt lgkmcnt(0)" ::: "memory");                            \
    __builtin_amdgcn_sched_barrier(0);                                            \
    bf16x8 pf0[2];                                                                \
    _Pragma("unroll") for (int kk2 = 0; kk2 < 2; ++kk2)                           \
        pf0[kk2] = *reinterpret_cast<const bf16x8*>(myp + proff[kk2]);            \
    __builtin_amdgcn_s_setprio(1);                                                \
    _Pragma("unroll") for (int nf = 0; nf < 4; ++nf)                              \
        _Pragma("unroll") for (int kk2 = 0; kk2 < 2; ++kk2) {                     \
            bf16x8 vf = *reinterpret_cast<const bf16x8*>(Vl + koff[nf][kk2]);     \
            acc0[nf] = __builtin_amdgcn_mfma_f32_16x16x32_bf16(vf, pf0[kk2], acc0[nf], 0, 0, 0); } \
    __builtin_amdgcn_s_setprio(0);                                                \
    /* qset1: reuse the SAME patch (in-order DS pipe) */                          \
    _Pragma("unroll") for (int t = 0; t < 4; ++t) {                               \
        float p10 = exp2f(s1[t][0]), p11 = exp2f(s1[t][1]);                       \
        float p12 = exp2f(s1[t][2]), p13 = exp2f(s1[t][3]);                       \
        l1 += (p10 + p11) + (p12 + p13);                                          \
        bf16x4 pw1 = { (bf16_t)p10, (bf16_t)p11, (bf16_t)p12, (bf16_t)p13 };      \
        *reinterpret_cast<bf16x4*>(myp + pwoff[t]) = pw1; }                       \
    asm volatile("s_waitcnt lgkmcnt(0)" ::: "memory");                            \
    __builtin_amdgcn_sched_barrier(0);                                            \
    bf16x8 pf1[2];                                                                \
    _Pragma("unroll") for (int kk2 = 0; kk2 < 2; ++kk2)                           \
        pf1[kk2] = *reinterpret_cast<const bf16x8*>(myp + proff[kk2]);            \
    __builtin_amdgcn_s_setprio(1);                                                \
    _Pragma("unroll") for (int nf = 0; nf < 4; ++nf)                              \
        _Pragma("unroll") for (int kk2 = 0; kk2 < 2; ++kk2) {                     \
            bf16x8 vf = *reinterpret_cast<const bf16x8*>(Vl + koff[nf][kk2]);     \
            acc1[nf] = __builtin_amdgcn_mfma_f32_16x16x32_bf16(vf, pf1[kk2], acc1[nf], 0, 0, 0); } \
    __builtin_amdgcn_s_setprio(0);                                                \
    asm volatile("s_waitcnt lgkmcnt(0)" ::: "memory");                            \
    __builtin_amdgcn_s_barrier();                                                 \
} while (0)

    STAGE2(kvbuf[0]);                    // tile `lo`; pointers now at lo+1
    #pragma unroll 1
    for (int it = 0; it < nt; it += 2) {
        ABODY(it,     kvbuf[0], kvbuf[1]);
        ABODY(it + 1, kvbuf[1], kvbuf[0]);
    }

    // cross-lane reduce of partial row sums
    l0 += __shfl_xor(l0, 16, 64);
    l0 += __shfl_xor(l0, 32, 64);
    l1 += __shfl_xor(l1, 16, 64);
    l1 += __shfl_xor(l1, 32, 64);

    if (mode == 0) {
        float inv0 = 1.f / l0, inv1 = 1.f / l1;
        #pragma unroll
        for (int nf = 0; nf < 4; ++nf) {
            bf16x4 ov0 = { (bf16_t)(acc0[nf][0] * inv0), (bf16_t)(acc0[nf][1] * inv0),
                           (bf16_t)(acc0[nf][2] * inv0), (bf16_t)(acc0[nf][3] * inv0) };
            *reinterpret_cast<bf16x4*>(
                out + (size_t)(b * T_ + qg0) * C_ + h * HD + nf * 16 + g * 4) = ov0;
            bf16x4 ov1 = { (bf16_t)(acc1[nf][0] * inv1), (bf16_t)(acc1[nf][1] * inv1),
                           (bf16_t)(acc1[nf][2] * inv1), (bf16_t)(acc1[nf][3] * inv1) };
            *reinterpret_cast<bf16x4*>(
                out + (size_t)(b * T_ + qg1) * C_ + h * HD + nf * 16 + g * 4) = ov1;
        }
    } else {
        // raw partial: acc bf16 [128][64] + l f32 [128]
        char* slot = pbuf + (size_t)((((bh << 3) + (qt - 8)) << 1) + (mode - 1)) * PSLOT;
        const int r0 = wid * 32 + q16, r1 = r0 + 16;
        #pragma unroll
        for (int nf = 0; nf < 4; ++nf) {
            bf16x4 a0 = { (bf16_t)acc0[nf][0], (bf16_t)acc0[nf][1],
                          (bf16_t)acc0[nf][2], (bf16_t)acc0[nf][3] };
            *reinterpret_cast<bf16x4*>(slot + r0 * 128 + (nf * 16 + g * 4) * 2) = a0;
            bf16x4 a1 = { (bf16_t)acc1[nf][0], (bf16_t)acc1[nf][1],
                          (bf16_t)acc1[nf][2], (bf16_t)acc1[nf][3] };
            *reinterpret_cast<bf16x4*>(slot + r1 * 128 + (nf * 16 + g * 4) * 2) = a1;
        }
        if (g == 0) {
            *reinterpret_cast<float*>(slot + 16384 + r0 * 4) = l0;
            *reinterpret_cast<float*>(slot + 16384 + r1 * 4) = l1;
        }
    }
#undef ABODY
#undef STAGE2
}

// ---------------- combine: out = (a0+a1)/(l0+l1) for split q-tiles ----------------
__global__ __launch_bounds__(256) void combine_kernel(
    const char* __restrict__ pbuf, bf16_t* __restrict__ out)
{
    const int qtm8 = blockIdx.x;   // 0..7  (qt = 8 + qtm8)
    const int bh   = blockIdx.y;   // 0..63
    const int qt   = qtm8 + 8;
    const int b = bh >> 4, h = bh & 15;
    const char* s0 = pbuf + (size_t)((((bh << 3) + qtm8) << 1) + 0) * PSLOT;
    const char* s1 = s0 + PSLOT;
    const int t   = threadIdx.x;
    const int row = t >> 1;
    const int c0  = (t & 1) * 32;
    float l = *reinterpret_cast<const float*>(s0 + 16384 + row * 4)
            + *reinterpret_cast<const float*>(s1 + 16384 + row * 4);
    float inv = 1.f / l;
    bf16_t* op = out + (size_t)(b * T_ + qt * 128 + row) * C_ + h * HD + c0;
    #pragma unroll
    for (int j = 0; j < 8; ++j) {
        bf16x4 a0 = *reinterpret_cast<const bf16x4*>(s0 + row * 128 + (c0 + j * 4) * 2);
        bf16x4 a1 = *reinterpret_cast<const bf16x4*>(s1 + row * 128 + (c0 + j * 4) * 2);
        bf16x4 o = { (bf16_t)(((float)a0[0] + (float)a1[0]) * inv),
                     (bf16_t)(((float)a0[1] + (float)a1[1]) * inv),
                     (bf16_t)(((float)a0[2] + (float)a1[2]) * inv),
                     (bf16_t)(((float)a0[3] + (float)a1[3]) * inv) };
        *reinterpret_cast<bf16x4*>(op + j * 4) = o;
    }
}

// ---------------- launch ----------------
extern "C" void kernel_launch(void* const* d_in, const int* in_sizes, int n_in,
                              void* d_out, int out_size, void* d_ws, size_t ws_size,
                              hipStream_t stream) {
    const float* x      = (const float*)d_in[0];
    const float* w_qkv  = (const float*)d_in[1];
    const float* w_proj = (const float*)d_in[2];
    float* out = (float*)d_out;

    char* ws = (char*)d_ws;
    bf16_t* xb     = (bf16_t*)(ws);                  // 16,777,216 B (reused as partial buf after QKV)
    bf16_t* wqkvT  = (bf16_t*)(ws + 16777216);       //  6,291,456 B (ditto)
    bf16_t* wprojT = (bf16_t*)(ws + 23068672);       //  2,097,152 B
    bf16_t* Qb     = (bf16_t*)(ws + 25165824);       // 16,777,216 B
    bf16_t* Kb     = (bf16_t*)(ws + 41943040);       // 16,777,216 B
    bf16_t* Vtb    = (bf16_t*)(ws + 58720256);       // 16,777,216 B
    bf16_t* attnb  = (bf16_t*)(ws + 75497472);       // 16,777,216 B
    char*   pbuf   = ws;                              // partials: 1024 x 16896 = 17.3MB < 23MB dead

    conv_x_kernel<<<2048, 256, 0, stream>>>(x, xb, (B_ * T_ * C_) / 4);
    transpose_w_kernel<<<dim3(3 * C_ / 32, C_ / 32), dim3(32, 8), 0, stream>>>(w_qkv, wqkvT, C_, 3 * C_);
    transpose_w_kernel<<<dim3(C_ / 32, C_ / 32), dim3(32, 8), 0, stream>>>(w_proj, wprojT, C_, C_);

    gemm_kernel<1><<<1536, 256, 0, stream>>>(
        xb, wqkvT, nullptr, Qb, Kb, Vtb, M_TOT, 3 * C_, C_);

    attn_kernel<<<1536, 256, 0, stream>>>(Qb, Kb, Vtb, attnb, pbuf);
    combine_kernel<<<dim3(8, 64), 256, 0, stream>>>(pbuf, attnb);

    gemm_kernel<0><<<512, 256, 0, stream>>>(
        attnb, wprojT, out, nullptr, nullptr, nullptr, M_TOT, C_, C_);
}

// Round 17
// 161.332 us; speedup vs baseline: 1.0636x; 1.0636x over previous
//
#include <hip/hip_runtime.h>
#include <hip/hip_bf16.h>
#include <stdint.h>

typedef __bf16 bf16_t;
typedef __bf16 bf16x4 __attribute__((ext_vector_type(4)));
typedef __bf16 bf16x8 __attribute__((ext_vector_type(8)));
typedef float  f32x4  __attribute__((ext_vector_type(4)));

#define B_    4
#define T_    2048
#define C_    1024
#define NH    16
#define HD    64
#define M_TOT (B_ * T_)   // 8192

// async global -> LDS, 16B per lane (dest must be wave-uniform base + lane*16)
__device__ __forceinline__ void gload16(const void* g, void* l) {
    __builtin_amdgcn_global_load_lds(
        (const __attribute__((address_space(1))) uint32_t*)g,
        (__attribute__((address_space(3))) uint32_t*)l, 16, 0, 0);
}

// ---------------- convert x (fp32) -> bf16, flat ----------------
__global__ void conv_x_kernel(const float* __restrict__ x, bf16_t* __restrict__ xb, int n4) {
    int i = blockIdx.x * blockDim.x + threadIdx.x;
    int stride = gridDim.x * blockDim.x;
    for (; i < n4; i += stride) {
        float4 v = reinterpret_cast<const float4*>(x)[i];
        union { bf16_t h[4]; uint2 u; } p;
        p.h[0] = (bf16_t)v.x; p.h[1] = (bf16_t)v.y;
        p.h[2] = (bf16_t)v.z; p.h[3] = (bf16_t)v.w;
        reinterpret_cast<uint2*>(xb)[i] = p.u;
    }
}

// ---------------- transpose + convert: w[K][N] fp32 -> wt[N][K] bf16 ----------------
__global__ void transpose_w_kernel(const float* __restrict__ w, bf16_t* __restrict__ wt,
                                   int K, int N) {
    __shared__ float tile[32][33];
    int n0 = blockIdx.x * 32, k0 = blockIdx.y * 32;
    int tx = threadIdx.x, ty = threadIdx.y;
    #pragma unroll
    for (int i = 0; i < 32; i += 8)
        tile[ty + i][tx] = w[(size_t)(k0 + ty + i) * N + n0 + tx];
    __syncthreads();
    #pragma unroll
    for (int i = 0; i < 32; i += 8)
        wt[(size_t)(n0 + ty + i) * K + k0 + tx] = (bf16_t)tile[tx][ty + i];
}

#define QSCALE 0.18033688011112042f   // (1/8) * log2(e)

// ---------------- 128x128 GEMM, 2 barriers per K-tile ----------------
// Per tile: vmcnt(8) [stage from 2 tiles ago retired] -> bar -> GREAD ->
// lgkm0 -> bar [all waves read] -> MFMA(0) | GST(same buf, t+2) | MFMA(2).
#define LA0 0
#define LA1 16384
#define LB0 32768
#define LB1 49152

#define GST(ptr, rbase, base, kt) do { int k0_ = ((kt) << 6) & (K - 1);           \
    _Pragma("unroll") for (int c_ = 0; c_ < 4; ++c_) {                            \
        int li_ = tid + c_ * 256; int row_ = li_ >> 3;                            \
        int sw_ = (li_ & 7) ^ (row_ & 7);                                         \
        gload16(ptr + (size_t)((rbase) + row_) * K + k0_ + sw_ * 8,               \
                lds + (base) + li_ * 16); } } while (0)

#define GREAD(abase, bbase) do {                                                  \
    _Pragma("unroll") for (int mi_ = 0; mi_ < 4; ++mi_)                           \
        _Pragma("unroll") for (int kk_ = 0; kk_ < 2; ++kk_) {                     \
            int row_  = wm * 64 + mi_ * 16 + q16;                                 \
            int byte_ = (row_ * 128 + kk_ * 64 + g * 16) ^ ((row_ & 7) << 4);     \
            af[mi_ * 2 + kk_] = *reinterpret_cast<const bf16x8*>(lds + (abase) + byte_); } \
    _Pragma("unroll") for (int n_ = 0; n_ < 4; ++n_)                              \
        _Pragma("unroll") for (int kk_ = 0; kk_ < 2; ++kk_) {                     \
            int row_  = wn * 64 + n_ * 16 + q16;                                  \
            int byte_ = (row_ * 128 + kk_ * 64 + g * 16) ^ ((row_ & 7) << 4);     \
            bfr[n_ * 2 + kk_] = *reinterpret_cast<const bf16x8*>(lds + (bbase) + byte_); } } while (0)

#define GMFMA(milo) do { __builtin_amdgcn_s_setprio(1);                           \
    _Pragma("unroll") for (int mi_ = 0; mi_ < 2; ++mi_)                           \
        _Pragma("unroll") for (int kk_ = 0; kk_ < 2; ++kk_)                       \
            _Pragma("unroll") for (int n_ = 0; n_ < 4; ++n_)                      \
                acc[(milo) + mi_][n_] = __builtin_amdgcn_mfma_f32_16x16x32_bf16(  \
                    af[((milo) + mi_) * 2 + kk_], bfr[n_ * 2 + kk_],              \
                    acc[(milo) + mi_][n_], 0, 0, 0);                              \
    __builtin_amdgcn_s_setprio(0); } while (0)

#define GTILE(abase, bbase, ktn) do {                                             \
    asm volatile("s_waitcnt vmcnt(8)" ::: "memory");                              \
    __builtin_amdgcn_s_barrier();                                                 \
    __builtin_amdgcn_sched_barrier(0);                                            \
    GREAD(abase, bbase);                                                          \
    asm volatile("s_waitcnt lgkmcnt(0)" ::: "memory");                            \
    __builtin_amdgcn_s_barrier();                                                 \
    __builtin_amdgcn_sched_barrier(0);                                            \
    GMFMA(0);                                                                     \
    GST(A, mbase, abase, ktn); GST(Bt, nbase, bbase, ktn);                        \
    __builtin_amdgcn_sched_barrier(0);                                            \
    GMFMA(2); } while (0)

template<int MODE>
__global__ __launch_bounds__(256, 2) void gemm_kernel(
    const bf16_t* __restrict__ A, const bf16_t* __restrict__ Bt,
    float* __restrict__ Cout,
    bf16_t* __restrict__ Qo, bf16_t* __restrict__ Ko, bf16_t* __restrict__ Vt,
    int M, int N, int K)
{
    __shared__ __align__(16) char lds[65536];
    const int tid  = threadIdx.x;
    const int lane = tid & 63;
    const int wid  = tid >> 6;
    const int wm   = wid >> 1, wn = wid & 1;
    const int q16  = lane & 15, g = lane >> 4;
    const int xcd = blockIdx.x & 7;
    const int i0  = blockIdx.x >> 3;
    const int mbase = (xcd * 8 + (i0 & 7)) * 128;
    const int nbase = (i0 >> 3) * 128;
    const int NITER = K >> 7;

    f32x4  acc[4][4] = {};
    bf16x8 af[8], bfr[8];

    GST(A, mbase, LA0, 0); GST(Bt, nbase, LB0, 0);
    GST(A, mbase, LA1, 1); GST(Bt, nbase, LB1, 1);

    #pragma unroll 1
    for (int i = 0; i < NITER; ++i) {
        GTILE(LA0, LB0, 2 * i + 2);
        GTILE(LA1, LB1, 2 * i + 3);
    }
    asm volatile("s_waitcnt vmcnt(0)" ::: "memory");   // drain tail junk prefetches

    // epilogue: C/D layout col = q16, row = g*4 + r
    #pragma unroll
    for (int mi = 0; mi < 4; ++mi) {
        #pragma unroll
        for (int n = 0; n < 4; ++n) {
            const int row0 = mbase + wm * 64 + mi * 16 + g * 4;
            const int col0 = nbase + wn * 64 + n * 16;
            if (MODE == 0) {
                #pragma unroll
                for (int r = 0; r < 4; ++r)
                    Cout[(size_t)(row0 + r) * N + col0 + q16] = acc[mi][n][r];
            } else {
                const int b = row0 >> 11, t0 = row0 & 2047;
                if (col0 < 1024) {
                    int h = col0 >> 6, d = (col0 & 63) + q16;
                    #pragma unroll
                    for (int r = 0; r < 4; ++r)
                        Qo[((size_t)(b * NH + h) * T_ + t0 + r) * HD + d] =
                            (bf16_t)(acc[mi][n][r] * QSCALE);
                } else if (col0 < 2048) {
                    int h = (col0 - 1024) >> 6, d = (col0 & 63) + q16;
                    #pragma unroll
                    for (int r = 0; r < 4; ++r)
                        Ko[((size_t)(b * NH + h) * T_ + t0 + r) * HD + d] =
                            (bf16_t)acc[mi][n][r];
                } else {
                    int h = (col0 - 2048) >> 6, d = (col0 & 63) + q16;
                    bf16x4 vv = { (bf16_t)acc[mi][n][0], (bf16_t)acc[mi][n][1],
                                  (bf16_t)acc[mi][n][2], (bf16_t)acc[mi][n][3] };
                    *reinterpret_cast<bf16x4*>(
                        Vt + ((size_t)(b * NH + h) * HD + d) * T_ + t0) = vv;
                }
            }
        }
    }
}

// ---------------- flash attention: round-12 structure, SINGLE barrier per iter ----------------
// Hazard proof for 1 barrier: stage into buffer X is issued AFTER the top
// barrier; every wave reaches that barrier only after its previous-iteration
// reads of X completed (enforced by the lgkm waits its PV MFMAs require).
// Loop: vmcnt(0) [prev stage landed] -> barrier -> STAGE(next) -> QK ->
// softmax -> P roundtrip -> PV. No end-of-iter barrier / lgkm drain.
// 48KB LDS, 3 blocks/CU (register-capped at 84 VGPR = 3 waves/SIMD).
// Grid 1024; CU classes {k,k+4,k+8,k+12} sum 68 iters. bid&7==bh&7 XCD-pins K/V.
__global__ __launch_bounds__(256, 3) void attn_kernel(
    const bf16_t* __restrict__ Q, const bf16_t* __restrict__ K,
    const bf16_t* __restrict__ Vt, bf16_t* __restrict__ out)
{
    __shared__ __align__(16) char kvbuf[2][16384];   // [buf][ K 8KB | V^T 8KB ]
    __shared__ __align__(16) char plds[4][4096];     // per-wave 2 x (16q x 64kv) bf16 P^T
    const int tid  = threadIdx.x;
    const int lane = tid & 63;
    const int wid  = tid >> 6;
    const int g    = lane >> 4;
    const int q16  = lane & 15;

    const int bid = blockIdx.x;          // 0..1023
    const int k   = bid >> 6;            // 0..15 dispatch class
    const int bh  = bid & 63;
    const int b   = bh >> 4, h = bh & 15;
    const int qt  = (k < 4) ? (15 - k) : (k < 8) ? (k + 4) : (k < 12) ? (k - 4) : (15 - k);

    const bf16_t* Qh = Q  + (size_t)bh * T_ * HD;
    const bf16_t* Kh = K  + (size_t)bh * T_ * HD;
    const bf16_t* Vh = Vt + (size_t)bh * HD * T_;
    char* myp = plds[wid];
    const int pswz = (q16 & 7) << 4;

    const int nt    = 2 * qt + 2;            // KV-64 tiles needed (always even)
    const int qbase = qt * 128 + wid * 32;
    const int qg0   = qbase + q16;
    const int qg1   = qbase + 16 + q16;

    // ---- loop-invariant LDS byte offsets ----
    int koff[4][2], pwoff[4], proff[2];
    #pragma unroll
    for (int t = 0; t < 4; ++t) {
        #pragma unroll
        for (int kk = 0; kk < 2; ++kk)
            koff[t][kk] = ((t * 16 + q16) * 128 + kk * 64 + g * 16) ^ pswz;
        pwoff[t] = (q16 * 128 + t * 32 + g * 8) ^ pswz;
    }
    proff[0] = (q16 * 128 + g * 16) ^ pswz;
    proff[1] = (q16 * 128 + 64 + g * 16) ^ pswz;

    // ---- moving per-lane staging pointers ----
    const int li0 = tid,        row0 = li0 >> 3, sw0 = (li0 & 7) ^ (row0 & 7);
    const int li1 = tid + 256,  row1 = li1 >> 3, sw1 = (li1 & 7) ^ (row1 & 7);
    const bf16_t* kS0 = Kh + (size_t)row0 * HD + sw0 * 8;   // +4096/tile
    const bf16_t* kS1 = Kh + (size_t)row1 * HD + sw1 * 8;
    const bf16_t* vS0 = Vh + (size_t)row0 * T_ + sw0 * 8;   // +64/tile
    const bf16_t* vS1 = Vh + (size_t)row1 * T_ + sw1 * 8;

#define STAGE2(buf) do {                                                          \
        gload16(kS0, (char*)(buf) + tid * 16);                                    \
        gload16(kS1, (char*)(buf) + 4096 + tid * 16);                             \
        gload16(vS0, (char*)(buf) + 8192 + tid * 16);                             \
        gload16(vS1, (char*)(buf) + 12288 + tid * 16);                            \
        kS0 += 4096; kS1 += 4096; vS0 += 64; vS1 += 64; } while (0)

    // Q fragments (B-operand), two q-sets
    bf16x8 qf0[2], qf1[2];
    #pragma unroll
    for (int kk = 0; kk < 2; ++kk) {
        qf0[kk] = *reinterpret_cast<const bf16x8*>(Qh + (size_t)qg0 * HD + kk * 32 + g * 8);
        qf1[kk] = *reinterpret_cast<const bf16x8*>(Qh + (size_t)qg1 * HD + kk * 32 + g * 8);
    }

    f32x4 acc0[4] = {}, acc1[4] = {};
    float l0 = 0.f, l1 = 0.f;            // per-lane partial row sums

#define ABODY(IT, CURB, NXTB) do {                                                \
    const int kv0 = (IT) << 6;                                                    \
    asm volatile("s_waitcnt vmcnt(0)" ::: "memory");   /* CURB landed (mine) */   \
    __builtin_amdgcn_s_barrier();                      /* all waves: landed+read-done */ \
    __builtin_amdgcn_sched_barrier(0);                                            \
    if ((IT) + 1 < nt) STAGE2(NXTB);                   /* safe: everyone read NXTB */ \
    const char* Kl = (const char*)(CURB);                                         \
    const char* Vl = (const char*)(CURB) + 8192;                                  \
    f32x4 s0[4] = {}, s1[4] = {};                                                 \
    __builtin_amdgcn_s_setprio(1);                                                \
    _Pragma("unroll") for (int t = 0; t < 4; ++t)                                 \
        _Pragma("unroll") for (int kk = 0; kk < 2; ++kk) {                        \
            bf16x8 kf = *reinterpret_cast<const bf16x8*>(Kl + koff[t][kk]);       \
            s0[t] = __builtin_amdgcn_mfma_f32_16x16x32_bf16(kf, qf0[kk], s0[t], 0, 0, 0); \
            s1[t] = __builtin_amdgcn_mfma_f32_16x16x32_bf16(kf, qf1[kk], s1[t], 0, 0, 0); } \
    __builtin_amdgcn_s_setprio(0);                                                \
    if (kv0 + 63 > qbase) {                                                       \
        _Pragma("unroll") for (int t = 0; t < 4; ++t)                             \
            _Pragma("unroll") for (int r = 0; r < 4; ++r) {                       \
                int kv = kv0 + t * 16 + g * 4 + r;                                \
                if (kv > qg0) s0[t][r] = -1e30f;                                  \
                if (kv > qg1) s1[t][r] = -1e30f; } }                              \
    _Pragma("unroll") for (int t = 0; t < 4; ++t) {                               \
        float p00 = exp2f(s0[t][0]), p01 = exp2f(s0[t][1]);                       \
        float p02 = exp2f(s0[t][2]), p03 = exp2f(s0[t][3]);                       \
        l0 += (p00 + p01) + (p02 + p03);                                          \
        bf16x4 pw0 = { (bf16_t)p00, (bf16_t)p01, (bf16_t)p02, (bf16_t)p03 };      \
        *reinterpret_cast<bf16x4*>(myp + pwoff[t]) = pw0;                         \
        float p10 = exp2f(s1[t][0]), p11 = exp2f(s1[t][1]);                       \
        float p12 = exp2f(s1[t][2]), p13 = exp2f(s1[t][3]);                       \
        l1 += (p10 + p11) + (p12 + p13);                                          \
        bf16x4 pw1 = { (bf16_t)p10, (bf16_t)p11, (bf16_t)p12, (bf16_t)p13 };      \
        *reinterpret_cast<bf16x4*>(myp + 2048 + pwoff[t]) = pw1; }                \
    asm volatile("s_waitcnt lgkmcnt(0)" ::: "memory");                            \
    __builtin_amdgcn_sched_barrier(0);                                            \
    bf16x8 pf0[2], pf1[2];                                                        \
    _Pragma("unroll") for (int kk2 = 0; kk2 < 2; ++kk2) {                         \
        pf0[kk2] = *reinterpret_cast<const bf16x8*>(myp + proff[kk2]);            \
        pf1[kk2] = *reinterpret_cast<const bf16x8*>(myp + 2048 + proff[kk2]); }   \
    __builtin_amdgcn_s_setprio(1);                                                \
    _Pragma("unroll") for (int nf = 0; nf < 4; ++nf)                              \
        _Pragma("unroll") for (int kk2 = 0; kk2 < 2; ++kk2) {                     \
            bf16x8 vf = *reinterpret_cast<const bf16x8*>(Vl + koff[nf][kk2]);     \
            acc0[nf] = __builtin_amdgcn_mfma_f32_16x16x32_bf16(vf, pf0[kk2], acc0[nf], 0, 0, 0); \
            acc1[nf] = __builtin_amdgcn_mfma_f32_16x16x32_bf16(vf, pf1[kk2], acc1[nf], 0, 0, 0); } \
    __builtin_amdgcn_s_setprio(0);                                                \
} while (0)

    STAGE2(kvbuf[0]);                    // tile 0; pointers now at tile 1
    #pragma unroll 1
    for (int it = 0; it < nt; it += 2) {
        ABODY(it,     kvbuf[0], kvbuf[1]);
        ABODY(it + 1, kvbuf[1], kvbuf[0]);
    }

    // one-time cross-lane reduce of the partial row sums; write out
    l0 += __shfl_xor(l0, 16, 64);
    l0 += __shfl_xor(l0, 32, 64);
    l1 += __shfl_xor(l1, 16, 64);
    l1 += __shfl_xor(l1, 32, 64);
    float inv0 = 1.f / l0, inv1 = 1.f / l1;
    #pragma unroll
    for (int nf = 0; nf < 4; ++nf) {
        bf16x4 ov0 = { (bf16_t)(acc0[nf][0] * inv0), (bf16_t)(acc0[nf][1] * inv0),
                       (bf16_t)(acc0[nf][2] * inv0), (bf16_t)(acc0[nf][3] * inv0) };
        *reinterpret_cast<bf16x4*>(
            out + (size_t)(b * T_ + qg0) * C_ + h * HD + nf * 16 + g * 4) = ov0;
        bf16x4 ov1 = { (bf16_t)(acc1[nf][0] * inv1), (bf16_t)(acc1[nf][1] * inv1),
                       (bf16_t)(acc1[nf][2] * inv1), (bf16_t)(acc1[nf][3] * inv1) };
        *reinterpret_cast<bf16x4*>(
            out + (size_t)(b * T_ + qg1) * C_ + h * HD + nf * 16 + g * 4) = ov1;
    }
#undef ABODY
#undef STAGE2
}

// ---------------- launch ----------------
extern "C" void kernel_launch(void* const* d_in, const int* in_sizes, int n_in,
                              void* d_out, int out_size, void* d_ws, size_t ws_size,
                              hipStream_t stream) {
    const float* x      = (const float*)d_in[0];
    const float* w_qkv  = (const float*)d_in[1];
    const float* w_proj = (const float*)d_in[2];
    float* out = (float*)d_out;

    char* ws = (char*)d_ws;
    bf16_t* xb     = (bf16_t*)(ws);                  // 16,777,216 B
    bf16_t* wqkvT  = (bf16_t*)(ws + 16777216);       //  6,291,456 B
    bf16_t* wprojT = (bf16_t*)(ws + 23068672);       //  2,097,152 B
    bf16_t* Qb     = (bf16_t*)(ws + 25165824);       // 16,777,216 B
    bf16_t* Kb     = (bf16_t*)(ws + 41943040);       // 16,777,216 B
    bf16_t* Vtb    = (bf16_t*)(ws + 58720256);       // 16,777,216 B
    bf16_t* attnb  = (bf16_t*)(ws + 75497472);       // 16,777,216 B

    conv_x_kernel<<<2048, 256, 0, stream>>>(x, xb, (B_ * T_ * C_) / 4);
    transpose_w_kernel<<<dim3(3 * C_ / 32, C_ / 32), dim3(32, 8), 0, stream>>>(w_qkv, wqkvT, C_, 3 * C_);
    transpose_w_kernel<<<dim3(C_ / 32, C_ / 32), dim3(32, 8), 0, stream>>>(w_proj, wprojT, C_, C_);

    // QKV: 8 M-tiles/XCD x 24 N-tiles x 8 XCDs = 1536 blocks (6/CU exact)
    gemm_kernel<1><<<1536, 256, 0, stream>>>(
        xb, wqkvT, nullptr, Qb, Kb, Vtb, M_TOT, 3 * C_, C_);

    attn_kernel<<<1024, 256, 0, stream>>>(Qb, Kb, Vtb, attnb);

    // proj: 8 M-tiles/XCD x 8 N-tiles x 8 XCDs = 512 blocks (2/CU exact)
    gemm_kernel<0><<<512, 256, 0, stream>>>(
        attnb, wprojT, out, nullptr, nullptr, nullptr, M_TOT, C_, C_);
}

// Round 18
// 156.182 us; speedup vs baseline: 1.0986x; 1.0330x over previous
//
#include <hip/hip_runtime.h>
#include <hip/hip_bf16.h>
#include <stdint.h>

typedef __bf16 bf16_t;
typedef __bf16 bf16x4 __attribute__((ext_vector_type(4)));
typedef __bf16 bf16x8 __attribute__((ext_vector_type(8)));
typedef float  f32x4  __attribute__((ext_vector_type(4)));

#define B_    4
#define T_    2048
#define C_    1024
#define NH    16
#define HD    64
#define M_TOT (B_ * T_)   // 8192

// async global -> LDS, 16B per lane (dest must be wave-uniform base + lane*16)
__device__ __forceinline__ void gload16(const void* g, void* l) {
    __builtin_amdgcn_global_load_lds(
        (const __attribute__((address_space(1))) uint32_t*)g,
        (__attribute__((address_space(3))) uint32_t*)l, 16, 0, 0);
}

// ---------------- convert x (fp32) -> bf16, flat ----------------
__global__ void conv_x_kernel(const float* __restrict__ x, bf16_t* __restrict__ xb, int n4) {
    int i = blockIdx.x * blockDim.x + threadIdx.x;
    int stride = gridDim.x * blockDim.x;
    for (; i < n4; i += stride) {
        float4 v = reinterpret_cast<const float4*>(x)[i];
        union { bf16_t h[4]; uint2 u; } p;
        p.h[0] = (bf16_t)v.x; p.h[1] = (bf16_t)v.y;
        p.h[2] = (bf16_t)v.z; p.h[3] = (bf16_t)v.w;
        reinterpret_cast<uint2*>(xb)[i] = p.u;
    }
}

// ---------------- fused transpose+convert of both weights ----------------
// bx < 96: w_qkv (N=3072) -> wqkvT ; bx >= 96: w_proj (N=1024) -> wprojT
__global__ void transpose_both_kernel(const float* __restrict__ wq, bf16_t* __restrict__ wqT,
                                      const float* __restrict__ wp, bf16_t* __restrict__ wpT) {
    __shared__ float tile[32][33];
    const int bx = blockIdx.x;
    const float* w; bf16_t* wt; int N, n0;
    if (bx < 96) { w = wq; wt = wqT; N = 3 * C_; n0 = bx * 32; }
    else         { w = wp; wt = wpT; N = C_;     n0 = (bx - 96) * 32; }
    const int K = C_;
    int k0 = blockIdx.y * 32;
    int tx = threadIdx.x, ty = threadIdx.y;
    #pragma unroll
    for (int i = 0; i < 32; i += 8)
        tile[ty + i][tx] = w[(size_t)(k0 + ty + i) * N + n0 + tx];
    __syncthreads();
    #pragma unroll
    for (int i = 0; i < 32; i += 8)
        wt[(size_t)(n0 + ty + i) * K + k0 + tx] = (bf16_t)tile[tx][ty + i];
}

#define QSCALE 0.18033688011112042f   // (1/8) * log2(e)

// ---------------- 128x128 GEMM, 2 barriers per K-tile ----------------
#define LA0 0
#define LA1 16384
#define LB0 32768
#define LB1 49152

#define GST(ptr, rbase, base, kt) do { int k0_ = ((kt) << 6) & (K - 1);           \
    _Pragma("unroll") for (int c_ = 0; c_ < 4; ++c_) {                            \
        int li_ = tid + c_ * 256; int row_ = li_ >> 3;                            \
        int sw_ = (li_ & 7) ^ (row_ & 7);                                         \
        gload16(ptr + (size_t)((rbase) + row_) * K + k0_ + sw_ * 8,               \
                lds + (base) + li_ * 16); } } while (0)

#define GREAD(abase, bbase) do {                                                  \
    _Pragma("unroll") for (int mi_ = 0; mi_ < 4; ++mi_)                           \
        _Pragma("unroll") for (int kk_ = 0; kk_ < 2; ++kk_) {                     \
            int row_  = wm * 64 + mi_ * 16 + q16;                                 \
            int byte_ = (row_ * 128 + kk_ * 64 + g * 16) ^ ((row_ & 7) << 4);     \
            af[mi_ * 2 + kk_] = *reinterpret_cast<const bf16x8*>(lds + (abase) + byte_); } \
    _Pragma("unroll") for (int n_ = 0; n_ < 4; ++n_)                              \
        _Pragma("unroll") for (int kk_ = 0; kk_ < 2; ++kk_) {                     \
            int row_  = wn * 64 + n_ * 16 + q16;                                  \
            int byte_ = (row_ * 128 + kk_ * 64 + g * 16) ^ ((row_ & 7) << 4);     \
            bfr[n_ * 2 + kk_] = *reinterpret_cast<const bf16x8*>(lds + (bbase) + byte_); } } while (0)

#define GMFMA(milo) do {                                                          \
    _Pragma("unroll") for (int mi_ = 0; mi_ < 2; ++mi_)                           \
        _Pragma("unroll") for (int kk_ = 0; kk_ < 2; ++kk_)                       \
            _Pragma("unroll") for (int n_ = 0; n_ < 4; ++n_)                      \
                acc[(milo) + mi_][n_] = __builtin_amdgcn_mfma_f32_16x16x32_bf16(  \
                    af[((milo) + mi_) * 2 + kk_], bfr[n_ * 2 + kk_],              \
                    acc[(milo) + mi_][n_], 0, 0, 0); } while (0)

#define GTILE(abase, bbase, ktn) do {                                             \
    asm volatile("s_waitcnt vmcnt(8)" ::: "memory");                              \
    __builtin_amdgcn_s_barrier();                                                 \
    __builtin_amdgcn_sched_barrier(0);                                            \
    GREAD(abase, bbase);                                                          \
    asm volatile("s_waitcnt lgkmcnt(0)" ::: "memory");                            \
    __builtin_amdgcn_s_barrier();                                                 \
    __builtin_amdgcn_sched_barrier(0);                                            \
    GMFMA(0);                                                                     \
    GST(A, mbase, abase, ktn); GST(Bt, nbase, bbase, ktn);                        \
    __builtin_amdgcn_sched_barrier(0);                                            \
    GMFMA(2); } while (0)

template<int MODE>
__global__ __launch_bounds__(256, 2) void gemm_kernel(
    const bf16_t* __restrict__ A, const bf16_t* __restrict__ Bt,
    float* __restrict__ Cout,
    bf16_t* __restrict__ Qo, bf16_t* __restrict__ Ko, bf16_t* __restrict__ Vt,
    int M, int N, int K)
{
    __shared__ __align__(16) char lds[65536];
    const int tid  = threadIdx.x;
    const int lane = tid & 63;
    const int wid  = tid >> 6;
    const int wm   = wid >> 1, wn = wid & 1;
    const int q16  = lane & 15, g = lane >> 4;
    const int xcd = blockIdx.x & 7;
    const int i0  = blockIdx.x >> 3;
    const int mbase = (xcd * 8 + (i0 & 7)) * 128;
    const int nbase = (i0 >> 3) * 128;
    const int NITER = K >> 7;

    f32x4  acc[4][4] = {};
    bf16x8 af[8], bfr[8];

    GST(A, mbase, LA0, 0); GST(Bt, nbase, LB0, 0);
    GST(A, mbase, LA1, 1); GST(Bt, nbase, LB1, 1);

    #pragma unroll 1
    for (int i = 0; i < NITER; ++i) {
        GTILE(LA0, LB0, 2 * i + 2);
        GTILE(LA1, LB1, 2 * i + 3);
    }
    asm volatile("s_waitcnt vmcnt(0)" ::: "memory");   // drain tail junk prefetches

    // epilogue: C/D layout col = q16, row = g*4 + r
    #pragma unroll
    for (int mi = 0; mi < 4; ++mi) {
        #pragma unroll
        for (int n = 0; n < 4; ++n) {
            const int row0 = mbase + wm * 64 + mi * 16 + g * 4;
            const int col0 = nbase + wn * 64 + n * 16;
            if (MODE == 0) {
                #pragma unroll
                for (int r = 0; r < 4; ++r)
                    Cout[(size_t)(row0 + r) * N + col0 + q16] = acc[mi][n][r];
            } else {
                const int b = row0 >> 11, t0 = row0 & 2047;
                if (col0 < 1024) {
                    int h = col0 >> 6, d = (col0 & 63) + q16;
                    #pragma unroll
                    for (int r = 0; r < 4; ++r)
                        Qo[((size_t)(b * NH + h) * T_ + t0 + r) * HD + d] =
                            (bf16_t)(acc[mi][n][r] * QSCALE);
                } else if (col0 < 2048) {
                    int h = (col0 - 1024) >> 6, d = (col0 & 63) + q16;
                    #pragma unroll
                    for (int r = 0; r < 4; ++r)
                        Ko[((size_t)(b * NH + h) * T_ + t0 + r) * HD + d] =
                            (bf16_t)acc[mi][n][r];
                } else {
                    int h = (col0 - 2048) >> 6, d = (col0 & 63) + q16;
                    bf16x4 vv = { (bf16_t)acc[mi][n][0], (bf16_t)acc[mi][n][1],
                                  (bf16_t)acc[mi][n][2], (bf16_t)acc[mi][n][3] };
                    *reinterpret_cast<bf16x4*>(
                        Vt + ((size_t)(b * NH + h) * HD + d) * T_ + t0) = vv;
                }
            }
        }
    }
}

// ---------------- flash attention: single barrier per iter + masked-tile skip ----------------
// Wave-uniform skip: tile kv0 is FULLY masked for this wave when kv0 >= qbase+32
// (waves 0,1 of every block waste exactly one tile). No interior barriers, so
// skipping compute is sync-safe; the wave still stages its share and hits the
// top barrier. Skipped p-values were exact zeros (exp2(-1e30) flushes).
// 48KB LDS, 3 blocks/CU (register-capped at 84 VGPR = 3 waves/SIMD).
// Grid 1024; CU classes {k,k+4,k+8,k+12} sum 68 iters. bid&7==bh&7 XCD-pins K/V.
__global__ __launch_bounds__(256, 3) void attn_kernel(
    const bf16_t* __restrict__ Q, const bf16_t* __restrict__ K,
    const bf16_t* __restrict__ Vt, bf16_t* __restrict__ out)
{
    __shared__ __align__(16) char kvbuf[2][16384];   // [buf][ K 8KB | V^T 8KB ]
    __shared__ __align__(16) char plds[4][4096];     // per-wave 2 x (16q x 64kv) bf16 P^T
    const int tid  = threadIdx.x;
    const int lane = tid & 63;
    const int wid  = tid >> 6;
    const int g    = lane >> 4;
    const int q16  = lane & 15;

    const int bid = blockIdx.x;          // 0..1023
    const int k   = bid >> 6;            // 0..15 dispatch class
    const int bh  = bid & 63;
    const int b   = bh >> 4, h = bh & 15;
    const int qt  = (k < 4) ? (15 - k) : (k < 8) ? (k + 4) : (k < 12) ? (k - 4) : (15 - k);

    const bf16_t* Qh = Q  + (size_t)bh * T_ * HD;
    const bf16_t* Kh = K  + (size_t)bh * T_ * HD;
    const bf16_t* Vh = Vt + (size_t)bh * HD * T_;
    char* myp = plds[wid];
    const int pswz = (q16 & 7) << 4;

    const int nt    = 2 * qt + 2;            // KV-64 tiles needed (always even)
    const int qbase = qt * 128 + wid * 32;
    const int qg0   = qbase + q16;
    const int qg1   = qbase + 16 + q16;

    // ---- loop-invariant LDS byte offsets ----
    int koff[4][2], pwoff[4], proff[2];
    #pragma unroll
    for (int t = 0; t < 4; ++t) {
        #pragma unroll
        for (int kk = 0; kk < 2; ++kk)
            koff[t][kk] = ((t * 16 + q16) * 128 + kk * 64 + g * 16) ^ pswz;
        pwoff[t] = (q16 * 128 + t * 32 + g * 8) ^ pswz;
    }
    proff[0] = (q16 * 128 + g * 16) ^ pswz;
    proff[1] = (q16 * 128 + 64 + g * 16) ^ pswz;

    // ---- moving per-lane staging pointers ----
    const int li0 = tid,        row0 = li0 >> 3, sw0 = (li0 & 7) ^ (row0 & 7);
    const int li1 = tid + 256,  row1 = li1 >> 3, sw1 = (li1 & 7) ^ (row1 & 7);
    const bf16_t* kS0 = Kh + (size_t)row0 * HD + sw0 * 8;   // +4096/tile
    const bf16_t* kS1 = Kh + (size_t)row1 * HD + sw1 * 8;
    const bf16_t* vS0 = Vh + (size_t)row0 * T_ + sw0 * 8;   // +64/tile
    const bf16_t* vS1 = Vh + (size_t)row1 * T_ + sw1 * 8;

#define STAGE2(buf) do {                                                          \
        gload16(kS0, (char*)(buf) + tid * 16);                                    \
        gload16(kS1, (char*)(buf) + 4096 + tid * 16);                             \
        gload16(vS0, (char*)(buf) + 8192 + tid * 16);                             \
        gload16(vS1, (char*)(buf) + 12288 + tid * 16);                            \
        kS0 += 4096; kS1 += 4096; vS0 += 64; vS1 += 64; } while (0)

    // Q fragments (B-operand), two q-sets
    bf16x8 qf0[2], qf1[2];
    #pragma unroll
    for (int kk = 0; kk < 2; ++kk) {
        qf0[kk] = *reinterpret_cast<const bf16x8*>(Qh + (size_t)qg0 * HD + kk * 32 + g * 8);
        qf1[kk] = *reinterpret_cast<const bf16x8*>(Qh + (size_t)qg1 * HD + kk * 32 + g * 8);
    }

    f32x4 acc0[4] = {}, acc1[4] = {};
    float l0 = 0.f, l1 = 0.f;            // per-lane partial row sums

#define ABODY(IT, CURB, NXTB) do {                                                \
    const int kv0 = (IT) << 6;                                                    \
    asm volatile("s_waitcnt vmcnt(0)" ::: "memory");   /* CURB landed (mine) */   \
    __builtin_amdgcn_s_barrier();                      /* all waves: landed+read-done */ \
    __builtin_amdgcn_sched_barrier(0);                                            \
    if ((IT) + 1 < nt) STAGE2(NXTB);                   /* safe: everyone read NXTB */ \
    if (kv0 < qbase + 32) {                            /* wave-uniform: skip fully-masked */ \
    const char* Kl = (const char*)(CURB);                                         \
    const char* Vl = (const char*)(CURB) + 8192;                                  \
    f32x4 s0[4] = {}, s1[4] = {};                                                 \
    __builtin_amdgcn_s_setprio(1);                                                \
    _Pragma("unroll") for (int t = 0; t < 4; ++t)                                 \
        _Pragma("unroll") for (int kk = 0; kk < 2; ++kk) {                        \
            bf16x8 kf = *reinterpret_cast<const bf16x8*>(Kl + koff[t][kk]);       \
            s0[t] = __builtin_amdgcn_mfma_f32_16x16x32_bf16(kf, qf0[kk], s0[t], 0, 0, 0); \
            s1[t] = __builtin_amdgcn_mfma_f32_16x16x32_bf16(kf, qf1[kk], s1[t], 0, 0, 0); } \
    __builtin_amdgcn_s_setprio(0);                                                \
    if (kv0 + 63 > qbase) {                                                       \
        _Pragma("unroll") for (int t = 0; t < 4; ++t)                             \
            _Pragma("unroll") for (int r = 0; r < 4; ++r) {                       \
                int kv = kv0 + t * 16 + g * 4 + r;                                \
                if (kv > qg0) s0[t][r] = -1e30f;                                  \
                if (kv > qg1) s1[t][r] = -1e30f; } }                              \
    _Pragma("unroll") for (int t = 0; t < 4; ++t) {                               \
        float p00 = exp2f(s0[t][0]), p01 = exp2f(s0[t][1]);                       \
        float p02 = exp2f(s0[t][2]), p03 = exp2f(s0[t][3]);                       \
        l0 += (p00 + p01) + (p02 + p03);                                          \
        bf16x4 pw0 = { (bf16_t)p00, (bf16_t)p01, (bf16_t)p02, (bf16_t)p03 };      \
        *reinterpret_cast<bf16x4*>(myp + pwoff[t]) = pw0;                         \
        float p10 = exp2f(s1[t][0]), p11 = exp2f(s1[t][1]);                       \
        float p12 = exp2f(s1[t][2]), p13 = exp2f(s1[t][3]);                       \
        l1 += (p10 + p11) + (p12 + p13);                                          \
        bf16x4 pw1 = { (bf16_t)p10, (bf16_t)p11, (bf16_t)p12, (bf16_t)p13 };      \
        *reinterpret_cast<bf16x4*>(myp + 2048 + pwoff[t]) = pw1; }                \
    asm volatile("s_waitcnt lgkmcnt(0)" ::: "memory");                            \
    __builtin_amdgcn_sched_barrier(0);                                            \
    bf16x8 pf0[2], pf1[2];                                                        \
    _Pragma("unroll") for (int kk2 = 0; kk2 < 2; ++kk2) {                         \
        pf0[kk2] = *reinterpret_cast<const bf16x8*>(myp + proff[kk2]);            \
        pf1[kk2] = *reinterpret_cast<const bf16x8*>(myp + 2048 + proff[kk2]); }   \
    __builtin_amdgcn_s_setprio(1);                                                \
    _Pragma("unroll") for (int nf = 0; nf < 4; ++nf)                              \
        _Pragma("unroll") for (int kk2 = 0; kk2 < 2; ++kk2) {                     \
            bf16x8 vf = *reinterpret_cast<const bf16x8*>(Vl + koff[nf][kk2]);     \
            acc0[nf] = __builtin_amdgcn_mfma_f32_16x16x32_bf16(vf, pf0[kk2], acc0[nf], 0, 0, 0); \
            acc1[nf] = __builtin_amdgcn_mfma_f32_16x16x32_bf16(vf, pf1[kk2], acc1[nf], 0, 0, 0); } \
    __builtin_amdgcn_s_setprio(0);                                                \
    }                                                                             \
} while (0)

    STAGE2(kvbuf[0]);                    // tile 0; pointers now at tile 1
    #pragma unroll 1
    for (int it = 0; it < nt; it += 2) {
        ABODY(it,     kvbuf[0], kvbuf[1]);
        ABODY(it + 1, kvbuf[1], kvbuf[0]);
    }
    asm volatile("s_waitcnt vmcnt(0)" ::: "memory");

    // one-time cross-lane reduce of the partial row sums; write out
    l0 += __shfl_xor(l0, 16, 64);
    l0 += __shfl_xor(l0, 32, 64);
    l1 += __shfl_xor(l1, 16, 64);
    l1 += __shfl_xor(l1, 32, 64);
    float inv0 = 1.f / l0, inv1 = 1.f / l1;
    #pragma unroll
    for (int nf = 0; nf < 4; ++nf) {
        bf16x4 ov0 = { (bf16_t)(acc0[nf][0] * inv0), (bf16_t)(acc0[nf][1] * inv0),
                       (bf16_t)(acc0[nf][2] * inv0), (bf16_t)(acc0[nf][3] * inv0) };
        *reinterpret_cast<bf16x4*>(
            out + (size_t)(b * T_ + qg0) * C_ + h * HD + nf * 16 + g * 4) = ov0;
        bf16x4 ov1 = { (bf16_t)(acc1[nf][0] * inv1), (bf16_t)(acc1[nf][1] * inv1),
                       (bf16_t)(acc1[nf][2] * inv1), (bf16_t)(acc1[nf][3] * inv1) };
        *reinterpret_cast<bf16x4*>(
            out + (size_t)(b * T_ + qg1) * C_ + h * HD + nf * 16 + g * 4) = ov1;
    }
#undef ABODY
#undef STAGE2
}

// ---------------- launch ----------------
extern "C" void kernel_launch(void* const* d_in, const int* in_sizes, int n_in,
                              void* d_out, int out_size, void* d_ws, size_t ws_size,
                              hipStream_t stream) {
    const float* x      = (const float*)d_in[0];
    const float* w_qkv  = (const float*)d_in[1];
    const float* w_proj = (const float*)d_in[2];
    float* out = (float*)d_out;

    char* ws = (char*)d_ws;
    bf16_t* xb     = (bf16_t*)(ws);                  // 16,777,216 B
    bf16_t* wqkvT  = (bf16_t*)(ws + 16777216);       //  6,291,456 B
    bf16_t* wprojT = (bf16_t*)(ws + 23068672);       //  2,097,152 B
    bf16_t* Qb     = (bf16_t*)(ws + 25165824);       // 16,777,216 B
    bf16_t* Kb     = (bf16_t*)(ws + 41943040);       // 16,777,216 B
    bf16_t* Vtb    = (bf16_t*)(ws + 58720256);       // 16,777,216 B
    bf16_t* attnb  = (bf16_t*)(ws + 75497472);       // 16,777,216 B

    conv_x_kernel<<<2048, 256, 0, stream>>>(x, xb, (B_ * T_ * C_) / 4);
    transpose_both_kernel<<<dim3(128, 32), dim3(32, 8), 0, stream>>>(w_qkv, wqkvT, w_proj, wprojT);

    // QKV: 8 M-tiles/XCD x 24 N-tiles x 8 XCDs = 1536 blocks (6/CU exact)
    gemm_kernel<1><<<1536, 256, 0, stream>>>(
        xb, wqkvT, nullptr, Qb, Kb, Vtb, M_TOT, 3 * C_, C_);

    attn_kernel<<<1024, 256, 0, stream>>>(Qb, Kb, Vtb, attnb);

    // proj: 8 M-tiles/XCD x 8 N-tiles x 8 XCDs = 512 blocks (2/CU exact)
    gemm_kernel<0><<<512, 256, 0, stream>>>(
        attnb, wprojT, out, nullptr, nullptr, nullptr, M_TOT, C_, C_);
}